// Round 11
// baseline (26.853 us; speedup 1.0000x reference)
//
#include <hip/hip_runtime.h>

#define D_MAX   50
#define T_DIM   51
#define B_DIM   16
#define P_DIM   2048
#define Q_DIM   2048
#define TSTRIDE 80            // bytes per t-row: 64 used (16 b * u32 pair) + 16 skew
#define PBY     4112          // LDS bytes per p-row (4080 + pad)
#define PSPAN   16            // p's per block -> LDS 65,792 B -> 2 blocks/CU
#define NPBLK   (P_DIM / PSPAN)        // 128
#define QB      512
#define PCHK    8             // W/DR pipeline chunk (2 chunks of 8 p)

// ws layout: partial float [NPBLK][B][Q] = 128*16*2048*4 = 16 MiB

// d = taps.lo*cw.lo + taps.hi*cw.hi + acc   (bf16 pair dot, f32 accumulate)
__device__ __forceinline__ float dot2bf(unsigned taps, unsigned cw, float acc) {
    float d;
    asm("v_dot2_f32_bf16 %0, %1, %2, %3" : "=v"(d) : "v"(taps), "v"(cw), "v"(acc));
    return d;
}
__device__ __forceinline__ unsigned pack_bf16x2(float lo, float hi) {
    unsigned r;
    asm("v_cvt_pk_bf16_f32 %0, %1, %2" : "=v"(r) : "v"(lo), "v"(hi));
    return r;
}

#define PREFETCH(wArr, xArr, cc)                                            \
    _Pragma("unroll")                                                       \
    for (int j = 0; j < PCHK; ++j) {                                        \
        wArr[j] = Wq[(size_t)(p0 + (cc) * PCHK + j) * Q_DIM];               \
        xArr[j] = Dq[(size_t)(p0 + (cc) * PCHK + j) * Q_DIM];               \
    }

#define COMPUTE8(wArr, xArr, cc)                                            \
    _Pragma("unroll")                                                       \
    for (int jj = 0; jj < PCHK; ++jj) {                                     \
        const int p = (cc) * PCHK + jj;                                     \
        const float w = wArr[jj], x = xArr[jj];                             \
        const float d = 50.f / (1.f + __expf(-x));                          \
        const int df = min((int)d, D_MAX);                                  \
        const float a  = d - (float)df;                                     \
        const float wa = w * a;                                             \
        const unsigned cw = pack_bf16x2(w - wa, wa);                        \
        const char* rb = lds + p * PBY + df * TSTRIDE;                      \
        const uint4 u0 = *(const uint4*)(rb);                               \
        const uint4 u1 = *(const uint4*)(rb + 16);                          \
        const uint4 u2 = *(const uint4*)(rb + 32);                          \
        const uint4 u3 = *(const uint4*)(rb + 48);                          \
        acc[0]  = dot2bf(u0.x, cw, acc[0]);                                 \
        acc[1]  = dot2bf(u0.y, cw, acc[1]);                                 \
        acc[2]  = dot2bf(u0.z, cw, acc[2]);                                 \
        acc[3]  = dot2bf(u0.w, cw, acc[3]);                                 \
        acc[4]  = dot2bf(u1.x, cw, acc[4]);                                 \
        acc[5]  = dot2bf(u1.y, cw, acc[5]);                                 \
        acc[6]  = dot2bf(u1.z, cw, acc[6]);                                 \
        acc[7]  = dot2bf(u1.w, cw, acc[7]);                                 \
        acc[8]  = dot2bf(u2.x, cw, acc[8]);                                 \
        acc[9]  = dot2bf(u2.y, cw, acc[9]);                                 \
        acc[10] = dot2bf(u2.z, cw, acc[10]);                                \
        acc[11] = dot2bf(u2.w, cw, acc[11]);                                \
        acc[12] = dot2bf(u3.x, cw, acc[12]);                                \
        acc[13] = dot2bf(u3.y, cw, acc[13]);                                \
        acc[14] = dot2bf(u3.z, cw, acc[14]);                                \
        acc[15] = dot2bf(u3.w, cw, acc[15]);                                \
    }

// Fused: block = 512 q-lanes x 16 p; 2 blocks/CU (pack VMEM of one block
// overlaps compute LDS of the other; 16 waves/CU). Phase 1: pack bf16
// tap-pair image into LDS. Phase 2: per p, sigmoid once, 4 ds_read_b128
// (one 64B skewed row = both taps for all 16 b), 16 v_dot2; W/DR
// register-double-buffered. Epilogue: f32 partial store (R9-proven).
__global__ __launch_bounds__(512, 4) void dsl_fused_kernel(
    const float* __restrict__ buf, const float* __restrict__ W,
    const float* __restrict__ DR, float* __restrict__ partial) {
    __shared__ char lds[PSPAN * PBY];   // 65,792 B
    const int tid = threadIdx.x;
    // 512 blocks = 4 q-cols x 128 p-slices; same-slice blocks are 128 apart
    // in dispatch order -> same XCD (128 % 8 == 0) -> shared L2 for buf.
    const int i  = blockIdx.x;
    const int xq = i >> 7;              // 0..3 q-column
    const int yp = i & 127;             // p-slice
    const int q  = xq * QB + tid;
    const int p0 = yp * PSPAN;

    // ---- phase 1: pack (R8-proven). thread = (b=tid>>5, th=(tid>>4)&1, p=tid&15)
    {
        const int bb = tid >> 5, th = (tid >> 4) & 1, pl = tid & 15;
        const int t0 = th * 26;         // th0: rows 0..25, th1: rows 26..50
        const float* src = buf + (size_t)bb * (T_DIM * P_DIM) + p0 + pl;
        float v[27];
#pragma unroll
        for (int j = 0; j < 27; ++j) {
            const int t = t0 + j;
            v[j] = (t <= 50) ? src[(size_t)t * P_DIM] : 0.f;
        }
        char* wb = lds + pl * PBY + bb * 4;
#pragma unroll
        for (int j = 0; j < 26; ++j) {
            const int t = t0 + j;
            if (t <= 50)
                *(unsigned*)(wb + t * TSTRIDE) = pack_bf16x2(v[j], v[j + 1]);
        }
    }

    // ---- chunk-0 W/DR preload (chunk-1 pipelined inside compute)
    const float* Wq = W + q;
    const float* Dq = DR + q;
    float wA[PCHK], xA[PCHK], wB[PCHK], xB[PCHK];
    PREFETCH(wA, xA, 0)
    __syncthreads();

    // ---- phase 2: compute
    float acc[B_DIM];
#pragma unroll
    for (int b = 0; b < B_DIM; ++b) acc[b] = 0.f;

    PREFETCH(wB, xB, 1)       // chunk-1 loads fly during chunk-0 compute
    COMPUTE8(wA, xA, 0)
    COMPUTE8(wB, xB, 1)

    float* dst = partial + (size_t)yp * (B_DIM * Q_DIM) + q;
#pragma unroll
    for (int b = 0; b < B_DIM; ++b)
        dst[(size_t)b * Q_DIM] = acc[b];      // coalesced along q
}

// Reduce: sum NPBLK f32 partials; block = 64 outputs x 4 c-waves, LDS combine.
__global__ __launch_bounds__(256) void dsl_reduce_kernel(
    const float* __restrict__ partial, float* __restrict__ out) {
    __shared__ float lds[4][64];
    const int j = threadIdx.x & 63, w = threadIdx.x >> 6;
    const int idx = blockIdx.x * 64 + j;              // idx = b*Q + q
    float s = 0.f;
    for (int c = w; c < NPBLK; c += 4)
        s += partial[(size_t)c * (B_DIM * Q_DIM) + idx];
    lds[w][j] = s;
    __syncthreads();
    if (w == 0)
        out[idx] = lds[0][j] + lds[1][j] + lds[2][j] + lds[3][j];
}

extern "C" void kernel_launch(void* const* d_in, const int* in_sizes, int n_in,
                              void* d_out, int out_size, void* d_ws, size_t ws_size,
                              hipStream_t stream) {
    const float* buf = (const float*)d_in[0];   // [B, T, P]
    const float* W   = (const float*)d_in[1];   // [P, Q]
    const float* DR  = (const float*)d_in[2];   // [P, Q]
    float* out = (float*)d_out;                 // [B, Q]

    float* partial = (float*)d_ws;              // [NPBLK][B][Q], 16 MiB

    hipLaunchKernelGGL(dsl_fused_kernel, dim3(4 * NPBLK), dim3(512), 0, stream,
                       buf, W, DR, partial);
    hipLaunchKernelGGL(dsl_reduce_kernel, dim3((B_DIM * Q_DIM) / 64), dim3(256), 0, stream,
                       partial, out);
}

// Round 12
// 23.182 us; speedup vs baseline: 1.1584x; 1.1584x over previous
//
#include <hip/hip_runtime.h>

#define D_MAX   50
#define T_DIM   51
#define B_DIM   16
#define P_DIM   2048
#define Q_DIM   2048
#define TSTRIDE 80            // bytes per t-row: 64 used (16 b * u32 pair) + 16 skew
#define PBY     4112          // LDS bytes per p-row (4080 + pad)
#define PHALF   16            // p's per LDS buffer (A/B halves)
#define PSPAN   32            // p's per block
#define NPBLK   (P_DIM / PSPAN)        // 64
#define QB      512
#define PCHK    8             // W/DR pipeline chunk (4 chunks of 8 p)

// ws layout: partial float [NPBLK][B][Q] = 64*16*2048*4 = 8 MiB

// d = taps.lo*cw.lo + taps.hi*cw.hi + acc   (bf16 pair dot, f32 accumulate)
__device__ __forceinline__ float dot2bf(unsigned taps, unsigned cw, float acc) {
    float d;
    asm("v_dot2_f32_bf16 %0, %1, %2, %3" : "=v"(d) : "v"(taps), "v"(cw), "v"(acc));
    return d;
}
__device__ __forceinline__ unsigned pack_bf16x2(float lo, float hi) {
    unsigned r;
    asm("v_cvt_pk_bf16_f32 %0, %1, %2" : "=v"(r) : "v"(lo), "v"(hi));
    return r;
}

#define PREFETCH(wArr, xArr, cc)                                            \
    _Pragma("unroll")                                                       \
    for (int j = 0; j < PCHK; ++j) {                                        \
        wArr[j] = Wq[(size_t)(p0 + (cc) * PCHK + j) * Q_DIM];               \
        xArr[j] = Dq[(size_t)(p0 + (cc) * PCHK + j) * Q_DIM];               \
    }

#define COMPUTE8(wArr, xArr, cc)                                            \
    _Pragma("unroll")                                                       \
    for (int jj = 0; jj < PCHK; ++jj) {                                     \
        const int p = (cc) * PCHK + jj;                                     \
        const float w = wArr[jj], x = xArr[jj];                             \
        const float d = 50.f / (1.f + __expf(-x));                          \
        const int df = min((int)d, D_MAX);                                  \
        const float a  = d - (float)df;                                     \
        const float wa = w * a;                                             \
        const unsigned cw = pack_bf16x2(w - wa, wa);                        \
        const char* rb = lds + p * PBY + df * TSTRIDE;                      \
        const uint4 u0 = *(const uint4*)(rb);                               \
        const uint4 u1 = *(const uint4*)(rb + 16);                          \
        const uint4 u2 = *(const uint4*)(rb + 32);                          \
        const uint4 u3 = *(const uint4*)(rb + 48);                          \
        acc[0]  = dot2bf(u0.x, cw, acc[0]);                                 \
        acc[1]  = dot2bf(u0.y, cw, acc[1]);                                 \
        acc[2]  = dot2bf(u0.z, cw, acc[2]);                                 \
        acc[3]  = dot2bf(u0.w, cw, acc[3]);                                 \
        acc[4]  = dot2bf(u1.x, cw, acc[4]);                                 \
        acc[5]  = dot2bf(u1.y, cw, acc[5]);                                 \
        acc[6]  = dot2bf(u1.z, cw, acc[6]);                                 \
        acc[7]  = dot2bf(u1.w, cw, acc[7]);                                 \
        acc[8]  = dot2bf(u2.x, cw, acc[8]);                                 \
        acc[9]  = dot2bf(u2.y, cw, acc[9]);                                 \
        acc[10] = dot2bf(u2.z, cw, acc[10]);                                \
        acc[11] = dot2bf(u2.w, cw, acc[11]);                                \
        acc[12] = dot2bf(u3.x, cw, acc[12]);                                \
        acc[13] = dot2bf(u3.y, cw, acc[13]);                                \
        acc[14] = dot2bf(u3.z, cw, acc[14]);                                \
        acc[15] = dot2bf(u3.w, cw, acc[15]);                                \
    }

// Fused (R9 + split pack): block = 512 q-lanes x 32 p as two 16-p LDS
// buffers. Pack A before barrier; B's loads issue after the barrier and
// stage in regs (latency hides under compute A), B's LDS write wedges
// between chunk computes (disjoint region). W/DR register-double-buffered.
__global__ __launch_bounds__(512, 2) void dsl_fused_kernel(
    const float* __restrict__ buf, const float* __restrict__ W,
    const float* __restrict__ DR, float* __restrict__ partial) {
    __shared__ char lds[PSPAN * PBY];   // 131,584 B (A: rows 0-15, B: 16-31)
    const int tid = threadIdx.x;
    // 256 blocks = 4 q-cols x 64 p-slices; same-slice blocks are 64 apart
    // in dispatch order -> same XCD (64 % 8 == 0) -> shared L2 for buf.
    const int i  = blockIdx.x;
    const int xq = i >> 6;                            // 0..3 q-column
    const int yp = ((i & 7) << 3) | ((i >> 3) & 7);   // bijective on [0,64)
    const int q  = xq * QB + tid;
    const int p0 = yp * PSPAN;

    // pack thread mapping (R8/R11-proven t-halved): (b, t-half, p) = 16x2x16
    const int bb = tid >> 5, th = (tid >> 4) & 1, pl = tid & 15;
    const int t0 = th * 26;             // th0: rows 0..25, th1: rows 26..50

    // ---- pack A (p0 .. p0+15), streamed
    {
        const float* src = buf + (size_t)bb * (T_DIM * P_DIM) + p0 + pl;
        float v[27];
#pragma unroll
        for (int j = 0; j < 27; ++j) {
            const int t = t0 + j;
            v[j] = (t <= 50) ? src[(size_t)t * P_DIM] : 0.f;
        }
        char* wb = lds + pl * PBY + bb * 4;
#pragma unroll
        for (int j = 0; j < 26; ++j) {
            const int t = t0 + j;
            if (t <= 50)
                *(unsigned*)(wb + t * TSTRIDE) = pack_bf16x2(v[j], v[j + 1]);
        }
    }

    // ---- chunk-0 W/DR preload
    const float* Wq = W + q;
    const float* Dq = DR + q;
    float wA[PCHK], xA[PCHK], wB[PCHK], xB[PCHK];
    PREFETCH(wA, xA, 0)
    __syncthreads();                    // A ready

    // ---- issue pack-B loads (p0+16 .. p0+31): latency hides under compute A
    float v2[27];
    {
        const float* src = buf + (size_t)bb * (T_DIM * P_DIM) + p0 + PHALF + pl;
#pragma unroll
        for (int j = 0; j < 27; ++j) {
            const int t = t0 + j;
            v2[j] = (t <= 50) ? src[(size_t)t * P_DIM] : 0.f;
        }
    }
    PREFETCH(wB, xB, 1)

    float acc[B_DIM];
#pragma unroll
    for (int b = 0; b < B_DIM; ++b) acc[b] = 0.f;

    COMPUTE8(wA, xA, 0)                 // A rows 0-7

    // ---- write pack-B into LDS rows 16-31 (disjoint from A: race-free)
    {
        char* wb = lds + (PHALF + pl) * PBY + bb * 4;
#pragma unroll
        for (int j = 0; j < 26; ++j) {
            const int t = t0 + j;
            if (t <= 50)
                *(unsigned*)(wb + t * TSTRIDE) = pack_bf16x2(v2[j], v2[j + 1]);
        }
    }
    PREFETCH(wA, xA, 2)
    COMPUTE8(wB, xB, 1)                 // A rows 8-15
    __syncthreads();                    // B ready (and everyone done with A)

    PREFETCH(wB, xB, 3)
    COMPUTE8(wA, xA, 2)                 // B rows 16-23
    COMPUTE8(wB, xB, 3)                 // B rows 24-31

    float* dst = partial + (size_t)yp * (B_DIM * Q_DIM) + q;
#pragma unroll
    for (int b = 0; b < B_DIM; ++b)
        dst[(size_t)b * Q_DIM] = acc[b];      // coalesced along q
}

// Reduce: sum NPBLK f32 partials; block = 64 outputs x 4 c-waves, LDS combine.
__global__ __launch_bounds__(256) void dsl_reduce_kernel(
    const float* __restrict__ partial, float* __restrict__ out) {
    __shared__ float lds[4][64];
    const int j = threadIdx.x & 63, w = threadIdx.x >> 6;
    const int idx = blockIdx.x * 64 + j;              // idx = b*Q + q
    float s = 0.f;
    for (int c = w; c < NPBLK; c += 4)
        s += partial[(size_t)c * (B_DIM * Q_DIM) + idx];
    lds[w][j] = s;
    __syncthreads();
    if (w == 0)
        out[idx] = lds[0][j] + lds[1][j] + lds[2][j] + lds[3][j];
}

extern "C" void kernel_launch(void* const* d_in, const int* in_sizes, int n_in,
                              void* d_out, int out_size, void* d_ws, size_t ws_size,
                              hipStream_t stream) {
    const float* buf = (const float*)d_in[0];   // [B, T, P]
    const float* W   = (const float*)d_in[1];   // [P, Q]
    const float* DR  = (const float*)d_in[2];   // [P, Q]
    float* out = (float*)d_out;                 // [B, Q]

    float* partial = (float*)d_ws;              // [NPBLK][B][Q], 8 MiB

    hipLaunchKernelGGL(dsl_fused_kernel, dim3(4 * NPBLK), dim3(512), 0, stream,
                       buf, W, DR, partial);
    hipLaunchKernelGGL(dsl_reduce_kernel, dim3((B_DIM * Q_DIM) / 64), dim3(256), 0, stream,
                       partial, out);
}

// Round 13
// 21.502 us; speedup vs baseline: 1.2488x; 1.0781x over previous
//
#include <hip/hip_runtime.h>

#define D_MAX   50
#define T_DIM   51
#define B_DIM   16
#define P_DIM   2048
#define Q_DIM   2048
#define TSTRIDE 80            // bytes per t-row: 64 used (16 b * u32 pair) + 16 skew
#define PBY     4112          // LDS bytes per p-row (4080 + pad)
#define PSPAN   32            // p's per block
#define NPBLK   (P_DIM / PSPAN)        // 64
#define QB      512
#define PCHK    8             // W/DR pipeline chunk (4 chunks of 8 p)

// ws layout: partial ushort(bf16) [NPBLK][B][Q] = 64*16*2048*2 = 4 MiB

// d = taps.lo*cw.lo + taps.hi*cw.hi + acc   (bf16 pair dot, f32 accumulate)
__device__ __forceinline__ float dot2bf(unsigned taps, unsigned cw, float acc) {
    float d;
    asm("v_dot2_f32_bf16 %0, %1, %2, %3" : "=v"(d) : "v"(taps), "v"(cw), "v"(acc));
    return d;
}
__device__ __forceinline__ unsigned pack_bf16x2(float lo, float hi) {
    unsigned r;
    asm("v_cvt_pk_bf16_f32 %0, %1, %2" : "=v"(r) : "v"(lo), "v"(hi));
    return r;
}
__device__ __forceinline__ unsigned short rne_bf16(float v) {
    unsigned x = __float_as_uint(v);
    x += 0x7fffu + ((x >> 16) & 1u);
    return (unsigned short)(x >> 16);
}

#define PREFETCH(wArr, xArr, cc)                                            \
    _Pragma("unroll")                                                       \
    for (int j = 0; j < PCHK; ++j) {                                        \
        wArr[j] = Wq[(size_t)(p0 + (cc) * PCHK + j) * Q_DIM];               \
        xArr[j] = Dq[(size_t)(p0 + (cc) * PCHK + j) * Q_DIM];               \
    }

#define COMPUTE8(wArr, xArr, cc)                                            \
    _Pragma("unroll")                                                       \
    for (int jj = 0; jj < PCHK; ++jj) {                                     \
        const int p = (cc) * PCHK + jj;                                     \
        const float w = wArr[jj], x = xArr[jj];                             \
        const float d = 50.f / (1.f + __expf(-x));                          \
        const int df = min((int)d, D_MAX);                                  \
        const float a  = d - (float)df;                                     \
        const float wa = w * a;                                             \
        const unsigned cw = pack_bf16x2(w - wa, wa);                        \
        const char* rb = lds + p * PBY + df * TSTRIDE;                      \
        const uint4 u0 = *(const uint4*)(rb);                               \
        const uint4 u1 = *(const uint4*)(rb + 16);                          \
        const uint4 u2 = *(const uint4*)(rb + 32);                          \
        const uint4 u3 = *(const uint4*)(rb + 48);                          \
        acc[0]  = dot2bf(u0.x, cw, acc[0]);                                 \
        acc[1]  = dot2bf(u0.y, cw, acc[1]);                                 \
        acc[2]  = dot2bf(u0.z, cw, acc[2]);                                 \
        acc[3]  = dot2bf(u0.w, cw, acc[3]);                                 \
        acc[4]  = dot2bf(u1.x, cw, acc[4]);                                 \
        acc[5]  = dot2bf(u1.y, cw, acc[5]);                                 \
        acc[6]  = dot2bf(u1.z, cw, acc[6]);                                 \
        acc[7]  = dot2bf(u1.w, cw, acc[7]);                                 \
        acc[8]  = dot2bf(u2.x, cw, acc[8]);                                 \
        acc[9]  = dot2bf(u2.y, cw, acc[9]);                                 \
        acc[10] = dot2bf(u2.z, cw, acc[10]);                                \
        acc[11] = dot2bf(u2.w, cw, acc[11]);                                \
        acc[12] = dot2bf(u3.x, cw, acc[12]);                                \
        acc[13] = dot2bf(u3.y, cw, acc[13]);                                \
        acc[14] = dot2bf(u3.z, cw, acc[14]);                                \
        acc[15] = dot2bf(u3.w, cw, acc[15]);                                \
    }

// Fused kernel (R9-exact, bf16 partial store): block = 512 q-lanes, 32 p.
// Phase 1: pack bf16 tap-pair image from buf into LDS (thread=(b,p) owns a
// t-run). Phase 2: 4 chunks of 8 p; chunk c+1's W/DR loads issue during
// chunk c's compute (register double-buffer); per p: sigmoid once, 4
// ds_read_b128 (one 64B skewed row = both taps for all 16 b), 16 v_dot2.
__global__ __launch_bounds__(512, 2) void dsl_fused_kernel(
    const float* __restrict__ buf, const float* __restrict__ W,
    const float* __restrict__ DR, unsigned short* __restrict__ partial) {
    __shared__ char lds[PSPAN * PBY];   // 131,584 B
    const int tid = threadIdx.x;
    // 256 blocks = 4 q-cols x 64 p-slices; the 4 blocks of one p-slice are
    // 64 apart in dispatch order -> same XCD (64 % 8 == 0) -> shared L2 buf.
    const int i  = blockIdx.x;
    const int xq = i >> 6;                            // 0..3 q-column
    const int yp = ((i & 7) << 3) | ((i >> 3) & 7);   // bijective on [0,64)
    const int q  = xq * QB + tid;
    const int p0 = yp * PSPAN;

    // ---- phase 1: pack. thread = (b = tid>>5, p = tid&31)
    {
        const int bb = tid >> 5, pl = tid & 31;
        const float* src = buf + (size_t)bb * (T_DIM * P_DIM) + p0 + pl;
        float v[T_DIM + 1];
#pragma unroll
        for (int t = 0; t < T_DIM; ++t)
            v[t] = src[(size_t)t * P_DIM];    // 2 x 128B segments per t per wave
        v[T_DIM] = 0.f;
        char* wb = lds + pl * PBY + bb * 4;
#pragma unroll
        for (int t = 0; t < T_DIM; ++t)       // row t holds (v[t], v[t+1])
            *(unsigned*)(wb + t * TSTRIDE) = pack_bf16x2(v[t], v[t + 1]);
    }

    // ---- chunk-0 W/DR preload only (rest pipelined inside compute)
    const float* Wq = W + q;
    const float* Dq = DR + q;
    float wA[PCHK], xA[PCHK], wB[PCHK], xB[PCHK];
    PREFETCH(wA, xA, 0)
    __syncthreads();

    // ---- phase 2: compute, register-double-buffered W/DR stream
    float acc[B_DIM];
#pragma unroll
    for (int b = 0; b < B_DIM; ++b) acc[b] = 0.f;

    PREFETCH(wB, xB, 1)       // chunk-1 loads fly during chunk-0 compute
    COMPUTE8(wA, xA, 0)
    PREFETCH(wA, xA, 2)
    COMPUTE8(wB, xB, 1)
    PREFETCH(wB, xB, 3)
    COMPUTE8(wA, xA, 2)
    COMPUTE8(wB, xB, 3)

    unsigned short* dst = partial + (size_t)yp * (B_DIM * Q_DIM) + q;
#pragma unroll
    for (int b = 0; b < B_DIM; ++b)
        dst[(size_t)b * Q_DIM] = rne_bf16(acc[b]);    // coalesced along q
}

// Reduce: sum NPBLK bf16 partials in f32; block = 64 outputs x 4 c-waves.
__global__ __launch_bounds__(256) void dsl_reduce_kernel(
    const unsigned short* __restrict__ partial, float* __restrict__ out) {
    __shared__ float lds[4][64];
    const int j = threadIdx.x & 63, w = threadIdx.x >> 6;
    const int idx = blockIdx.x * 64 + j;              // idx = b*Q + q
    float s = 0.f;
    for (int c = w; c < NPBLK; c += 4) {
        const unsigned u = partial[(size_t)c * (B_DIM * Q_DIM) + idx];
        s += __uint_as_float(u << 16);
    }
    lds[w][j] = s;
    __syncthreads();
    if (w == 0)
        out[idx] = lds[0][j] + lds[1][j] + lds[2][j] + lds[3][j];
}

extern "C" void kernel_launch(void* const* d_in, const int* in_sizes, int n_in,
                              void* d_out, int out_size, void* d_ws, size_t ws_size,
                              hipStream_t stream) {
    const float* buf = (const float*)d_in[0];   // [B, T, P]
    const float* W   = (const float*)d_in[1];   // [P, Q]
    const float* DR  = (const float*)d_in[2];   // [P, Q]
    float* out = (float*)d_out;                 // [B, Q]

    unsigned short* partial = (unsigned short*)d_ws;  // [NPBLK][B][Q], 4 MiB

    hipLaunchKernelGGL(dsl_fused_kernel, dim3(256), dim3(512), 0, stream,
                       buf, W, DR, partial);
    hipLaunchKernelGGL(dsl_reduce_kernel, dim3((B_DIM * Q_DIM) / 64), dim3(256), 0, stream,
                       partial, out);
}